// Round 8
// baseline (197.130 us; speedup 1.0000x reference)
//
#include <hip/hip_runtime.h>
#include <cstdint>

// MultiheadRCDA: N=8, L=300, HH=WW=96, E=256, NH=8, HD=32
// Round 8: vproj v6 — ZERO-barrier wave-independent design. Wave owns 32
// channels (B hoisted) x 18 tiles; 16 independent float4 loads/tile;
// v_cvt_pk_bf16_f32 packing; per-wave Ts transpose epilogue (DS in-order).

typedef __attribute__((ext_vector_type(8))) short short8v;  // bf16x8 MFMA frag
typedef __attribute__((ext_vector_type(4))) short short4v;  // 8B packed bf16
typedef __attribute__((ext_vector_type(4))) float f32x4;

#define SCALE_Q 0.17677669529663687f  // 32^-0.5

__device__ __forceinline__ unsigned short f2bf(float x) {
  unsigned int u = __builtin_bit_cast(unsigned int, x);
  u += 0x7FFFu + ((u >> 16) & 1u);
  return (unsigned short)(u >> 16);
}

__device__ __forceinline__ unsigned int cvtpk(float a, float b) {
  unsigned int r;
  asm("v_cvt_pk_bf16_f32 %0, %1, %2" : "=v"(r) : "v"(a), "v"(b));
  return r;
}

__device__ __forceinline__ short8v pack8cvt(const f32x4& lo, const f32x4& hi) {
  union { short8v s; unsigned int u[4]; } z;
  z.u[0] = cvtpk(lo[0], lo[1]);
  z.u[1] = cvtpk(lo[2], lo[3]);
  z.u[2] = cvtpk(hi[0], hi[1]);
  z.u[3] = cvtpk(hi[2], hi[3]);
  return z.s;
}

__device__ __forceinline__ short4v pack4cvt(float a, float b, float c, float d) {
  union { short4v s; unsigned int u[2]; } z;
  z.u[0] = cvtpk(a, b);
  z.u[1] = cvtpk(c, d);
  return z.s;
}

__device__ __forceinline__ short8v pack8(const float4& fa, const float4& fb) {
  short8v v;
  v[0] = (short)f2bf(fa.x); v[1] = (short)f2bf(fa.y);
  v[2] = (short)f2bf(fa.z); v[3] = (short)f2bf(fa.w);
  v[4] = (short)f2bf(fb.x); v[5] = (short)f2bf(fb.y);
  v[6] = (short)f2bf(fb.z); v[7] = (short)f2bf(fb.w);
  return v;
}

// ---------------- weight fp32->bf16 ----------------
__global__ __launch_bounds__(256) void cvt_w_kernel(const float* __restrict__ w_in,
                                                    const float* __restrict__ w_out,
                                                    short* __restrict__ Wb) {
  int idx = blockIdx.x * 256 + threadIdx.x;  // 393216 total
  float v = (idx < 327680) ? w_in[idx] : w_out[idx - 327680];
  Wb[idx] = (short)f2bf(v);
}

// ---------------- mean kernels v3 ----------------
__global__ __launch_bounds__(256) void mean_over_h_v3(const float* __restrict__ in,
                                                      float* __restrict__ out) {
  __shared__ float4 part[256];
  int bw = blockIdx.x;  // b*96 + w
  int b = bw / 96, w = bw - b * 96;
  int t = threadIdx.x, e4 = t & 63, hq = t >> 6;
  const float4* p = (const float4*)(in + ((size_t)b * 9216 + w) * 256) + e4 +
                    (size_t)hq * 24 * 6144;
  float4 s = {0.f, 0.f, 0.f, 0.f};
#pragma unroll
  for (int i = 0; i < 24; ++i) {
    float4 v = p[(size_t)i * 6144];
    s.x += v.x; s.y += v.y; s.z += v.z; s.w += v.w;
  }
  part[t] = s;
  __syncthreads();
  if (t < 64) {
    float4 a = part[t], c = part[t + 64], d = part[t + 128], e = part[t + 192];
    float4 o;
    o.x = (a.x + c.x + d.x + e.x) * (1.f / 96.f);
    o.y = (a.y + c.y + d.y + e.y) * (1.f / 96.f);
    o.z = (a.z + c.z + d.z + e.z) * (1.f / 96.f);
    o.w = (a.w + c.w + d.w + e.w) * (1.f / 96.f);
    ((float4*)out)[(size_t)bw * 64 + t] = o;
  }
}

__global__ __launch_bounds__(256) void mean_over_w_v3(const float* __restrict__ in,
                                                      float* __restrict__ out) {
  __shared__ float4 part[256];
  int bh = blockIdx.x;  // b*96 + h
  int t = threadIdx.x, e4 = t & 63, wq = t >> 6;
  const float4* p = (const float4*)(in + (size_t)bh * 24576) + e4 + (size_t)wq * 24 * 64;
  float4 s = {0.f, 0.f, 0.f, 0.f};
#pragma unroll
  for (int i = 0; i < 24; ++i) {
    float4 v = p[(size_t)i * 64];
    s.x += v.x; s.y += v.y; s.z += v.z; s.w += v.w;
  }
  part[t] = s;
  __syncthreads();
  if (t < 64) {
    float4 a = part[t], c = part[t + 64], d = part[t + 128], e = part[t + 192];
    float4 o;
    o.x = (a.x + c.x + d.x + e.x) * (1.f / 96.f);
    o.y = (a.y + c.y + d.y + e.y) * (1.f / 96.f);
    o.z = (a.z + c.z + d.z + e.z) * (1.f / 96.f);
    o.w = (a.w + c.w + d.w + e.w) * (1.f / 96.f);
    ((float4*)out)[(size_t)bh * 64 + t] = o;
  }
}

// ---------------- bf16 MFMA projection GEMM (q/k/out), BM=32 ----------------
__global__ __launch_bounds__(256) void gemm_proj(
    const float* __restrict__ A0, const float* __restrict__ A1,
    const short* __restrict__ Wb, const float* __restrict__ bias,
    float* __restrict__ Cf, short* __restrict__ Cb0, short* __restrict__ Cb1,
    float scale, int mode) {
  __shared__ short As[32 * 264];
  int y = blockIdx.y;
  const float* A = y ? A1 : A0;
  short* Cb = y ? Cb1 : Cb0;
  const short* Wp = Wb + y * 65536;
  const float* bp = bias + y * 256;
  int t = threadIdx.x;
  int m0 = blockIdx.x * 32;
  int wave = t >> 6, lane = t & 63, r = lane & 15, g = lane >> 4;

  {
    int row = t >> 3, c0 = (t & 7) * 32;
    const float* ap = A + ((size_t)m0 + row) * 256 + c0;
    float4 ld[8];
#pragma unroll
    for (int j = 0; j < 8; ++j) ld[j] = *(const float4*)(ap + j * 4);
    short* dst = &As[row * 264 + c0];
#pragma unroll
    for (int j = 0; j < 4; ++j)
      *(short8v*)(dst + j * 8) = pack8(ld[2 * j], ld[2 * j + 1]);
  }
  __syncthreads();

  f32x4 acc[2][4] = {};
  const short* wbase = Wp + (size_t)(wave * 64 + r) * 256;
#pragma unroll
  for (int ks = 0; ks < 8; ++ks) {
    short8v af0 = *(const short8v*)&As[r * 264 + ks * 32 + g * 8];
    short8v af1 = *(const short8v*)&As[(16 + r) * 264 + ks * 32 + g * 8];
    short8v bf[4];
#pragma unroll
    for (int nf = 0; nf < 4; ++nf)
      bf[nf] = *(const short8v*)(wbase + nf * 16 * 256 + ks * 32 + g * 8);
#pragma unroll
    for (int nf = 0; nf < 4; ++nf) {
      acc[0][nf] = __builtin_amdgcn_mfma_f32_16x16x32_bf16(af0, bf[nf], acc[0][nf], 0, 0, 0);
      acc[1][nf] = __builtin_amdgcn_mfma_f32_16x16x32_bf16(af1, bf[nf], acc[1][nf], 0, 0, 0);
    }
  }

#pragma unroll
  for (int mf = 0; mf < 2; ++mf)
#pragma unroll
    for (int nf = 0; nf < 4; ++nf) {
      int nn = wave * 64 + nf * 16 + r;
      float bval = bp[nn];
#pragma unroll
      for (int i = 0; i < 4; ++i) {
        int m = m0 + mf * 16 + g * 4 + i;
        float val = (acc[mf][nf][i] + bval) * scale;
        if (mode == 1) {
          int bb = m / 300, ll = m - bb * 300;
          Cf[((size_t)ll * 8 + bb) * 256 + nn] = val;
        } else {  // mode 3
          Cb[(size_t)m * 256 + nn] = (short)f2bf(val);
        }
      }
    }
}

// ---------------- value projection v6 (zero-barrier, wave-independent) ------
// vvT[bn][d(32)][hw(9216)] bf16.
// grid 512: blockIdx&1 = channel half (128 ch), blockIdx>>1 = tilegroup of
// 18 x 16-row tiles (288 rows; 256 groups). Wave owns 32 channels.
__global__ __launch_bounds__(256) void vproj_kernel(
    const float* __restrict__ A, const short* __restrict__ Wb,
    const float* __restrict__ bias, short* __restrict__ vvT) {
  __shared__ short Ts[4 * 32 * 36];  // per-wave private 32ch x (32hw pad36)
  int t = threadIdx.x;
  int wave = t >> 6, lane = t & 63, r = lane & 15, g = lane >> 4;
  int chgrp = blockIdx.x & 1, tg = blockIdx.x >> 1;
  int chbase = chgrp * 128 + wave * 32;

  // hoist B-frags for this wave's 32 channels: 16 loads, 64 VGPR
  short8v bf[8][2];
#pragma unroll
  for (int ks = 0; ks < 8; ++ks)
#pragma unroll
    for (int nf = 0; nf < 2; ++nf)
      bf[ks][nf] = *(const short8v*)(Wb + (size_t)(chbase + nf * 16 + r) * 256 +
                                     ks * 32 + g * 8);
  float bias_v[2];
#pragma unroll
  for (int nf = 0; nf < 2; ++nf) bias_v[nf] = bias[chbase + nf * 16 + r];

  short* tsw = &Ts[wave * 1152];
  int chg = chbase + (lane & 31);          // this lane's store channel
  int half = lane >> 5;
  const short* tsr = tsw + (lane & 31) * 36 + half * 16;
  short* vbase = vvT + (size_t)(chg >> 5) * 294912 + (size_t)(chg & 31) * 9216 +
                 half * 16;  // + b_*8*294912 + hw0 at store time

  for (int tt = 0; tt < 18; ++tt) {
    int m0 = (tg * 18 + tt) * 16;
    // 16 independent float4 loads (256 B in flight per thread)
    const float* ap = A + (size_t)(m0 + r) * 256 + g * 8;
    float4 ld[16];
#pragma unroll
    for (int ks = 0; ks < 8; ++ks) {
      ld[2 * ks]     = *(const float4*)(ap + ks * 32);
      ld[2 * ks + 1] = *(const float4*)(ap + ks * 32 + 4);
    }
    f32x4 acc[2] = {};
#pragma unroll
    for (int ks = 0; ks < 8; ++ks) {
      short8v af = pack8cvt(*(const f32x4*)&ld[2 * ks], *(const f32x4*)&ld[2 * ks + 1]);
      acc[0] = __builtin_amdgcn_mfma_f32_16x16x32_bf16(af, bf[ks][0], acc[0], 0, 0, 0);
      acc[1] = __builtin_amdgcn_mfma_f32_16x16x32_bf16(af, bf[ks][1], acc[1], 0, 0, 0);
    }
    // write to per-wave Ts (DS ops are in-order per wave; no barrier needed)
    int par = tt & 1;
#pragma unroll
    for (int nf = 0; nf < 2; ++nf) {
      float bv = bias_v[nf];
      *(short4v*)&tsw[(nf * 16 + r) * 36 + par * 16 + g * 4] =
          pack4cvt(acc[nf][0] + bv, acc[nf][1] + bv, acc[nf][2] + bv, acc[nf][3] + bv);
    }
    asm volatile("" ::: "memory");
    if (par) {  // store pair (tt-1, tt): 32 consecutive hw per channel
      int m0e = m0 - 16;
      int b_ = m0e / 9216, hw0 = m0e - b_ * 9216;
      short* gdst = vbase + (size_t)b_ * 8 * 294912 + hw0;
      *(short8v*)(gdst)     = *(const short8v*)(tsr);
      *(short8v*)(gdst + 8) = *(const short8v*)(tsr + 8);
      asm volatile("" ::: "memory");
    }
  }
}

// ---------------- scores + softmax: MFMA + in-register softmax ----------------
__global__ __launch_bounds__(64) void scores_softmax_v2(
    const short* __restrict__ qrb, const short* __restrict__ qcb,
    const short* __restrict__ krb, const short* __restrict__ kcb,
    short* __restrict__ wrowB, float* __restrict__ wcolT) {
  int lchunk = blockIdx.x, bn = blockIdx.y, kind = blockIdx.z;
  int b = bn >> 3, n = bn & 7;
  int lane = threadIdx.x;
  int r = lane & 15, g = lane >> 4;
  const short* qb = kind ? qcb : qrb;
  const short* kb = kind ? kcb : krb;
  int l0 = lchunk * 80;

  short8v a[5], bfr[6];
#pragma unroll
  for (int lf = 0; lf < 5; ++lf) {
    int l = l0 + lf * 16 + r;
    if (l > 299) l = 299;
    a[lf] = *(const short8v*)(qb + ((size_t)b * 300 + l) * 256 + n * 32 + g * 8);
  }
#pragma unroll
  for (int f = 0; f < 6; ++f)
    bfr[f] = *(const short8v*)(kb + ((size_t)b * 96 + f * 16 + r) * 256 + n * 32 + g * 8);

  f32x4 c[5][6];
#pragma unroll
  for (int lf = 0; lf < 5; ++lf)
#pragma unroll
    for (int f = 0; f < 6; ++f) {
      f32x4 z = {};
      c[lf][f] = __builtin_amdgcn_mfma_f32_16x16x32_bf16(a[lf], bfr[f], z, 0, 0, 0);
    }

#pragma unroll
  for (int lf = 0; lf < 5; ++lf)
#pragma unroll
    for (int i = 0; i < 4; ++i) {
      float m = c[lf][0][i];
#pragma unroll
      for (int f = 1; f < 6; ++f) m = fmaxf(m, c[lf][f][i]);
#pragma unroll
      for (int mask = 1; mask <= 8; mask <<= 1) m = fmaxf(m, __shfl_xor(m, mask, 64));
      float e[6], s = 0.f;
#pragma unroll
      for (int f = 0; f < 6; ++f) { e[f] = __expf(c[lf][f][i] - m); s += e[f]; }
#pragma unroll
      for (int mask = 1; mask <= 8; mask <<= 1) s += __shfl_xor(s, mask, 64);
      float inv = 1.f / s;
#pragma unroll
      for (int f = 0; f < 6; ++f) c[lf][f][i] = e[f] * inv;
    }

  if (kind == 0) {
#pragma unroll
    for (int lf = 0; lf < 5; ++lf)
#pragma unroll
      for (int i = 0; i < 4; ++i) {
        int l = l0 + lf * 16 + g * 4 + i;
        bool ok = (l < 300);
#pragma unroll
        for (int f = 0; f < 6; ++f) {
          float wv = ok ? c[lf][f][i] : 0.f;
          wrowB[((size_t)bn * 320 + l) * 96 + f * 16 + r] = (short)f2bf(wv);
        }
      }
  } else {
#pragma unroll
    for (int lf = 0; lf < 5; ++lf)
#pragma unroll
      for (int f = 0; f < 6; ++f) {
        int l = l0 + lf * 16 + g * 4;
        f32x4 wv = c[lf][f];
#pragma unroll
        for (int i = 0; i < 4; ++i) if (l + i >= 300) wv[i] = 0.f;
        *(f32x4*)(wcolT + ((size_t)bn * 96 + f * 16 + r) * 320 + l) = wv;
      }
  }
}

// ---------------- fused bilinear attention (MFMA, 8 waves) ----------------
__global__ __launch_bounds__(512) void attn_kernel(
    const short* __restrict__ wrowB, const float* __restrict__ wcolT,
    const short* __restrict__ vvT, float* __restrict__ ao) {
  __shared__ f32x4 cmb[3][2][4][64];
  int lh = blockIdx.x, n = blockIdx.y, b = blockIdx.z;
  int bn = b * 8 + n;
  int t = threadIdx.x, wave = t >> 6, lane = t & 63;
  int df = wave & 1, hh = wave >> 1;
  int lbase = lh * 64;
  int r = lane & 15, g = lane >> 4;

  short8v a[4][3];
  const short* wr = wrowB + (size_t)bn * 320 * 96;
#pragma unroll
  for (int lf = 0; lf < 4; ++lf)
#pragma unroll
    for (int ks = 0; ks < 3; ++ks)
      a[lf][ks] = *(const short8v*)(wr + (lbase + lf * 16 + r) * 96 + ks * 32 + g * 8);

  const short* vb = vvT + (size_t)bn * 294912 + (size_t)(df * 16 + r) * 9216 + hh * 24 * 96;
  const float* wcb = wcolT + ((size_t)bn * 96 + hh * 24) * 320 + lbase + g * 4;

  f32x4 acc[4] = {};
  short8v b0[3], b1[3];
  f32x4 w0[4], w1[4];
#pragma unroll
  for (int ks = 0; ks < 3; ++ks) b0[ks] = *(const short8v*)(vb + ks * 32 + g * 8);
#pragma unroll
  for (int lf = 0; lf < 4; ++lf) w0[lf] = *(const f32x4*)(wcb + lf * 16);

  for (int h2 = 0; h2 < 12; ++h2) {
    int h = h2 * 2;
#pragma unroll
    for (int ks = 0; ks < 3; ++ks) b1[ks] = *(const short8v*)(vb + (h + 1) * 96 + ks * 32 + g * 8);
#pragma unroll
    for (int lf = 0; lf < 4; ++lf) w1[lf] = *(const f32x4*)(wcb + (h + 1) * 320 + lf * 16);
    {
      f32x4 R[4] = {};
#pragma unroll
      for (int ks = 0; ks < 3; ++ks)
#pragma unroll
        for (int lf = 0; lf < 4; ++lf)
          R[lf] = __builtin_amdgcn_mfma_f32_16x16x32_bf16(a[lf][ks], b0[ks], R[lf], 0, 0, 0);
#pragma unroll
      for (int lf = 0; lf < 4; ++lf) acc[lf] += w0[lf] * R[lf];
    }
    if (h2 < 11) {
#pragma unroll
      for (int ks = 0; ks < 3; ++ks) b0[ks] = *(const short8v*)(vb + (h + 2) * 96 + ks * 32 + g * 8);
#pragma unroll
      for (int lf = 0; lf < 4; ++lf) w0[lf] = *(const f32x4*)(wcb + (h + 2) * 320 + lf * 16);
    }
    {
      f32x4 R[4] = {};
#pragma unroll
      for (int ks = 0; ks < 3; ++ks)
#pragma unroll
        for (int lf = 0; lf < 4; ++lf)
          R[lf] = __builtin_amdgcn_mfma_f32_16x16x32_bf16(a[lf][ks], b1[ks], R[lf], 0, 0, 0);
#pragma unroll
      for (int lf = 0; lf < 4; ++lf) acc[lf] += w1[lf] * R[lf];
    }
  }

  if (hh > 0) {
#pragma unroll
    for (int lf = 0; lf < 4; ++lf) cmb[hh - 1][df][lf][lane] = acc[lf];
  }
  __syncthreads();
  if (hh == 0) {
#pragma unroll
    for (int lf = 0; lf < 4; ++lf) {
      f32x4 o = acc[lf];
#pragma unroll
      for (int q = 0; q < 3; ++q) o += cmb[q][df][lf][lane];
#pragma unroll
      for (int i = 0; i < 4; ++i) {
        int l = lbase + lf * 16 + g * 4 + i;
        if (l < 300)
          ao[((size_t)b * 300 + l) * 256 + n * 32 + df * 16 + r] = o[i];
      }
    }
  }
}

// ---------------- launch ----------------
extern "C" void kernel_launch(void* const* d_in, const int* in_sizes, int n_in,
                              void* d_out, int out_size, void* d_ws, size_t ws_size,
                              hipStream_t stream) {
  const float* query_row = (const float*)d_in[0];
  const float* query_col = (const float*)d_in[1];
  const float* key_row   = (const float*)d_in[2];
  const float* key_col   = (const float*)d_in[3];
  const float* value     = (const float*)d_in[4];
  const float* W         = (const float*)d_in[5];  // (1280,256)
  const float* Bv        = (const float*)d_in[6];  // (1280,)
  const float* Wout      = (const float*)d_in[7];  // (256,256)
  const float* Bout      = (const float*)d_in[8];  // (256,)

  float* ws = (float*)d_ws;
  float* krm   = ws;                        // 196608 f
  float* kcm   = krm + 196608;              // 196608 f
  float* ao    = kcm + 196608;              // 614400 f
  float* wcolT = ao + 614400;               // 1966080 f
  short* qrb   = (short*)(wcolT + 1966080); // 614400 s
  short* qcb   = qrb + 614400;              // 614400 s
  short* krb   = qcb + 614400;              // 196608 s
  short* kcb   = krb + 196608;              // 196608 s
  short* wrowB = kcb + 196608;              // 1966080 s
  short* vvT   = wrowB + 1966080;           // 18874368 s
  short* Wb    = vvT + 18874368;            // 393216 s

  cvt_w_kernel<<<1536, 256, 0, stream>>>(W, Wout, Wb);
  mean_over_h_v3<<<768, 256, 0, stream>>>(key_row, krm);
  mean_over_w_v3<<<768, 256, 0, stream>>>(key_col, kcm);
  gemm_proj<<<dim3(75, 2), 256, 0, stream>>>(query_row, query_col, Wb, Bv,
                                             nullptr, qrb, qcb, SCALE_Q, 3);
  gemm_proj<<<dim3(24, 2), 256, 0, stream>>>(krm, kcm, Wb + 131072, Bv + 512,
                                             nullptr, krb, kcb, 1.f, 3);
  vproj_kernel<<<512, 256, 0, stream>>>(value, Wb + 262144, Bv + 1024, vvT);
  scores_softmax_v2<<<dim3(4, 64, 2), 64, 0, stream>>>(qrb, qcb, krb, kcb, wrowB, wcolT);
  attn_kernel<<<dim3(5, 8, 8), 512, 0, stream>>>(wrowB, wcolT, vvT, ao);
  gemm_proj<<<dim3(75, 1), 256, 0, stream>>>(ao, nullptr, Wb + 327680, Bout,
                                             (float*)d_out, nullptr, nullptr, 1.f, 1);
}

// Round 9
// 175.270 us; speedup vs baseline: 1.1247x; 1.1247x over previous
//
#include <hip/hip_runtime.h>
#include <cstdint>

// MultiheadRCDA: N=8, L=300, HH=WW=96, E=256, NH=8, HD=32
// Round 9: vproj v7 — issue-once + counted-vmcnt pipeline.
//  * A staged ONCE per block via linear-row global_load_lds into padded-row LDS
//    (row stride 1040B -> natural frag reads ~4-way max, no swizzle needed)
//  * B weights hoisted to 128 VGPR once per block (no per-ks L2 re-reads)
//  * all GLLs issued in prologue; per-tile asm s_waitcnt vmcnt(N) + raw
//    s_barrier (loads span barriers; no vmcnt(0) drain in loop)

typedef __attribute__((ext_vector_type(8))) short short8v;  // bf16x8 MFMA frag
typedef __attribute__((ext_vector_type(4))) short short4v;  // 8B packed bf16
typedef __attribute__((ext_vector_type(4))) float f32x4;

#define SCALE_Q 0.17677669529663687f  // 32^-0.5

#define GLL16(gp, lp)                                                   \
  __builtin_amdgcn_global_load_lds(                                     \
      (const __attribute__((address_space(1))) void*)(gp),              \
      (__attribute__((address_space(3))) void*)(lp), 16, 0, 0)

__device__ __forceinline__ unsigned short f2bf(float x) {
  unsigned int u = __builtin_bit_cast(unsigned int, x);
  u += 0x7FFFu + ((u >> 16) & 1u);
  return (unsigned short)(u >> 16);
}

__device__ __forceinline__ unsigned int cvtpk(float a, float b) {
  unsigned int r;
  asm("v_cvt_pk_bf16_f32 %0, %1, %2" : "=v"(r) : "v"(a), "v"(b));
  return r;
}

__device__ __forceinline__ short8v pack8cvt(const f32x4& lo, const f32x4& hi) {
  union { short8v s; unsigned int u[4]; } z;
  z.u[0] = cvtpk(lo[0], lo[1]);
  z.u[1] = cvtpk(lo[2], lo[3]);
  z.u[2] = cvtpk(hi[0], hi[1]);
  z.u[3] = cvtpk(hi[2], hi[3]);
  return z.s;
}

__device__ __forceinline__ short4v pack4cvt(float a, float b, float c, float d) {
  union { short4v s; unsigned int u[2]; } z;
  z.u[0] = cvtpk(a, b);
  z.u[1] = cvtpk(c, d);
  return z.s;
}

__device__ __forceinline__ short8v pack8(const float4& fa, const float4& fb) {
  short8v v;
  v[0] = (short)f2bf(fa.x); v[1] = (short)f2bf(fa.y);
  v[2] = (short)f2bf(fa.z); v[3] = (short)f2bf(fa.w);
  v[4] = (short)f2bf(fb.x); v[5] = (short)f2bf(fb.y);
  v[6] = (short)f2bf(fb.z); v[7] = (short)f2bf(fb.w);
  return v;
}

// ---------------- weight fp32->bf16 ----------------
__global__ __launch_bounds__(256) void cvt_w_kernel(const float* __restrict__ w_in,
                                                    const float* __restrict__ w_out,
                                                    short* __restrict__ Wb) {
  int idx = blockIdx.x * 256 + threadIdx.x;  // 393216 total
  float v = (idx < 327680) ? w_in[idx] : w_out[idx - 327680];
  Wb[idx] = (short)f2bf(v);
}

// ---------------- mean kernels v3 ----------------
__global__ __launch_bounds__(256) void mean_over_h_v3(const float* __restrict__ in,
                                                      float* __restrict__ out) {
  __shared__ float4 part[256];
  int bw = blockIdx.x;  // b*96 + w
  int b = bw / 96, w = bw - b * 96;
  int t = threadIdx.x, e4 = t & 63, hq = t >> 6;
  const float4* p = (const float4*)(in + ((size_t)b * 9216 + w) * 256) + e4 +
                    (size_t)hq * 24 * 6144;
  float4 s = {0.f, 0.f, 0.f, 0.f};
#pragma unroll
  for (int i = 0; i < 24; ++i) {
    float4 v = p[(size_t)i * 6144];
    s.x += v.x; s.y += v.y; s.z += v.z; s.w += v.w;
  }
  part[t] = s;
  __syncthreads();
  if (t < 64) {
    float4 a = part[t], c = part[t + 64], d = part[t + 128], e = part[t + 192];
    float4 o;
    o.x = (a.x + c.x + d.x + e.x) * (1.f / 96.f);
    o.y = (a.y + c.y + d.y + e.y) * (1.f / 96.f);
    o.z = (a.z + c.z + d.z + e.z) * (1.f / 96.f);
    o.w = (a.w + c.w + d.w + e.w) * (1.f / 96.f);
    ((float4*)out)[(size_t)bw * 64 + t] = o;
  }
}

__global__ __launch_bounds__(256) void mean_over_w_v3(const float* __restrict__ in,
                                                      float* __restrict__ out) {
  __shared__ float4 part[256];
  int bh = blockIdx.x;  // b*96 + h
  int t = threadIdx.x, e4 = t & 63, wq = t >> 6;
  const float4* p = (const float4*)(in + (size_t)bh * 24576) + e4 + (size_t)wq * 24 * 64;
  float4 s = {0.f, 0.f, 0.f, 0.f};
#pragma unroll
  for (int i = 0; i < 24; ++i) {
    float4 v = p[(size_t)i * 64];
    s.x += v.x; s.y += v.y; s.z += v.z; s.w += v.w;
  }
  part[t] = s;
  __syncthreads();
  if (t < 64) {
    float4 a = part[t], c = part[t + 64], d = part[t + 128], e = part[t + 192];
    float4 o;
    o.x = (a.x + c.x + d.x + e.x) * (1.f / 96.f);
    o.y = (a.y + c.y + d.y + e.y) * (1.f / 96.f);
    o.z = (a.z + c.z + d.z + e.z) * (1.f / 96.f);
    o.w = (a.w + c.w + d.w + e.w) * (1.f / 96.f);
    ((float4*)out)[(size_t)bh * 64 + t] = o;
  }
}

// ---------------- bf16 MFMA projection GEMM (q/k/out), BM=32 ----------------
__global__ __launch_bounds__(256) void gemm_proj(
    const float* __restrict__ A0, const float* __restrict__ A1,
    const short* __restrict__ Wb, const float* __restrict__ bias,
    float* __restrict__ Cf, short* __restrict__ Cb0, short* __restrict__ Cb1,
    float scale, int mode) {
  __shared__ short As[32 * 264];
  int y = blockIdx.y;
  const float* A = y ? A1 : A0;
  short* Cb = y ? Cb1 : Cb0;
  const short* Wp = Wb + y * 65536;
  const float* bp = bias + y * 256;
  int t = threadIdx.x;
  int m0 = blockIdx.x * 32;
  int wave = t >> 6, lane = t & 63, r = lane & 15, g = lane >> 4;

  {
    int row = t >> 3, c0 = (t & 7) * 32;
    const float* ap = A + ((size_t)m0 + row) * 256 + c0;
    float4 ld[8];
#pragma unroll
    for (int j = 0; j < 8; ++j) ld[j] = *(const float4*)(ap + j * 4);
    short* dst = &As[row * 264 + c0];
#pragma unroll
    for (int j = 0; j < 4; ++j)
      *(short8v*)(dst + j * 8) = pack8(ld[2 * j], ld[2 * j + 1]);
  }
  __syncthreads();

  f32x4 acc[2][4] = {};
  const short* wbase = Wp + (size_t)(wave * 64 + r) * 256;
#pragma unroll
  for (int ks = 0; ks < 8; ++ks) {
    short8v af0 = *(const short8v*)&As[r * 264 + ks * 32 + g * 8];
    short8v af1 = *(const short8v*)&As[(16 + r) * 264 + ks * 32 + g * 8];
    short8v bf[4];
#pragma unroll
    for (int nf = 0; nf < 4; ++nf)
      bf[nf] = *(const short8v*)(wbase + nf * 16 * 256 + ks * 32 + g * 8);
#pragma unroll
    for (int nf = 0; nf < 4; ++nf) {
      acc[0][nf] = __builtin_amdgcn_mfma_f32_16x16x32_bf16(af0, bf[nf], acc[0][nf], 0, 0, 0);
      acc[1][nf] = __builtin_amdgcn_mfma_f32_16x16x32_bf16(af1, bf[nf], acc[1][nf], 0, 0, 0);
    }
  }

#pragma unroll
  for (int mf = 0; mf < 2; ++mf)
#pragma unroll
    for (int nf = 0; nf < 4; ++nf) {
      int nn = wave * 64 + nf * 16 + r;
      float bval = bp[nn];
#pragma unroll
      for (int i = 0; i < 4; ++i) {
        int m = m0 + mf * 16 + g * 4 + i;
        float val = (acc[mf][nf][i] + bval) * scale;
        if (mode == 1) {
          int bb = m / 300, ll = m - bb * 300;
          Cf[((size_t)ll * 8 + bb) * 256 + nn] = val;
        } else {  // mode 3
          Cb[(size_t)m * 256 + nn] = (short)f2bf(val);
        }
      }
    }
}

// ---------------- value projection v7 ----------------
// vvT[bn][d(32)][hw(9216)] bf16. grid 2304 blocks; block = 2 tiles of 16 rows
// (rows bx*32..+32), 4 waves x 64 output channels (all 256 ch, B hoisted).
// LDS rows padded to 1040B so natural frag reads are ~4-way max.
__global__ __launch_bounds__(256, 2) void vproj_kernel(
    const float* __restrict__ A, const short* __restrict__ Wb,
    const float* __restrict__ bias, short* __restrict__ vvT) {
  __shared__ float buf[2][16 * 260];   // 2 x 16.6 KB, row stride 260 floats
  __shared__ short Ts[4][64 * 20];     // per-wave 64ch x (16hw pad20)
  int t = threadIdx.x;
  int wave = t >> 6, lane = t & 63, r = lane & 15, g = lane >> 4;
  int m0g = blockIdx.x * 32;
  int b_ = blockIdx.x / 288;            // 288 blocks per batch (9216/32)
  int hw00 = m0g - b_ * 9216;

  // hoist B: wave's 64 output channels, full K. 32 frags = 128 VGPR.
  short8v bf[8][4];
  const short* wbase = Wb + (size_t)(wave * 64 + r) * 256;
#pragma unroll
  for (int ks = 0; ks < 8; ++ks)
#pragma unroll
    for (int nf = 0; nf < 4; ++nf)
      bf[ks][nf] = *(const short8v*)(wbase + nf * 16 * 256 + ks * 32 + g * 8);
  float bias_v[4];
#pragma unroll
  for (int nf = 0; nf < 4; ++nf) bias_v[nf] = bias[wave * 64 + nf * 16 + r];

  // prologue: stage BOTH tiles via GLL (linear rows; wave w stages rows 4w..4w+3)
#pragma unroll
  for (int tt = 0; tt < 2; ++tt) {
#pragma unroll
    for (int i = 0; i < 4; ++i) {
      int row = wave * 4 + i;
      const float* gp = A + ((size_t)m0g + tt * 16 + row) * 256 + lane * 4;
      GLL16(gp, &buf[tt][row * 260]);
    }
  }

  // lane's store mapping: channel = wave*64 + lane
  int chg = wave * 64 + lane;
  short* vbase = vvT + (size_t)(b_ * 8 + (chg >> 5)) * 294912 +
                 (size_t)(chg & 31) * 9216 + hw00;
  const short* tsr = &Ts[wave][lane * 20];

#pragma unroll
  for (int tt = 0; tt < 2; ++tt) {
    if (tt == 0) {
      asm volatile("s_waitcnt vmcnt(4)" ::: "memory");  // tile0's 4 GLLs done
    } else {
      asm volatile("s_waitcnt vmcnt(2)" ::: "memory");  // tile1 done (2 stores newer)
    }
    __builtin_amdgcn_s_barrier();                       // all waves' parts done

    // compute: natural frag reads from padded rows
    f32x4 acc[4] = {};
    const float* bp_ = &buf[tt][0];
#pragma unroll
    for (int ks = 0; ks < 8; ++ks) {
      const float* p = bp_ + r * 260 + ks * 32 + g * 8;
      f32x4 lo = *(const f32x4*)p;
      f32x4 hi = *(const f32x4*)(p + 4);
      short8v af = pack8cvt(lo, hi);
#pragma unroll
      for (int nf = 0; nf < 4; ++nf)
        acc[nf] = __builtin_amdgcn_mfma_f32_16x16x32_bf16(af, bf[ks][nf], acc[nf], 0, 0, 0);
    }

    // transpose via per-wave Ts (wave-private; DS in-order per wave)
#pragma unroll
    for (int nf = 0; nf < 4; ++nf) {
      float bv = bias_v[nf];
      *(short4v*)&Ts[wave][(nf * 16 + r) * 20 + g * 4] =
          pack4cvt(acc[nf][0] + bv, acc[nf][1] + bv, acc[nf][2] + bv, acc[nf][3] + bv);
    }
    asm volatile("" ::: "memory");
    // store this tile's 16 hw for lane's channel: 2 x 16B (pairs with the other
    // tile to fill each 64B line; same block -> L2 merge)
    short* gdst = vbase + tt * 16;
    *(short8v*)gdst = *(const short8v*)tsr;
    *(short8v*)(gdst + 8) = *(const short8v*)(tsr + 8);
    asm volatile("" ::: "memory");
  }
}

// ---------------- scores + softmax: MFMA + in-register softmax ----------------
__global__ __launch_bounds__(64) void scores_softmax_v2(
    const short* __restrict__ qrb, const short* __restrict__ qcb,
    const short* __restrict__ krb, const short* __restrict__ kcb,
    short* __restrict__ wrowB, float* __restrict__ wcolT) {
  int lchunk = blockIdx.x, bn = blockIdx.y, kind = blockIdx.z;
  int b = bn >> 3, n = bn & 7;
  int lane = threadIdx.x;
  int r = lane & 15, g = lane >> 4;
  const short* qb = kind ? qcb : qrb;
  const short* kb = kind ? kcb : krb;
  int l0 = lchunk * 80;

  short8v a[5], bfr[6];
#pragma unroll
  for (int lf = 0; lf < 5; ++lf) {
    int l = l0 + lf * 16 + r;
    if (l > 299) l = 299;
    a[lf] = *(const short8v*)(qb + ((size_t)b * 300 + l) * 256 + n * 32 + g * 8);
  }
#pragma unroll
  for (int f = 0; f < 6; ++f)
    bfr[f] = *(const short8v*)(kb + ((size_t)b * 96 + f * 16 + r) * 256 + n * 32 + g * 8);

  f32x4 c[5][6];
#pragma unroll
  for (int lf = 0; lf < 5; ++lf)
#pragma unroll
    for (int f = 0; f < 6; ++f) {
      f32x4 z = {};
      c[lf][f] = __builtin_amdgcn_mfma_f32_16x16x32_bf16(a[lf], bfr[f], z, 0, 0, 0);
    }

#pragma unroll
  for (int lf = 0; lf < 5; ++lf)
#pragma unroll
    for (int i = 0; i < 4; ++i) {
      float m = c[lf][0][i];
#pragma unroll
      for (int f = 1; f < 6; ++f) m = fmaxf(m, c[lf][f][i]);
#pragma unroll
      for (int mask = 1; mask <= 8; mask <<= 1) m = fmaxf(m, __shfl_xor(m, mask, 64));
      float e[6], s = 0.f;
#pragma unroll
      for (int f = 0; f < 6; ++f) { e[f] = __expf(c[lf][f][i] - m); s += e[f]; }
#pragma unroll
      for (int mask = 1; mask <= 8; mask <<= 1) s += __shfl_xor(s, mask, 64);
      float inv = 1.f / s;
#pragma unroll
      for (int f = 0; f < 6; ++f) c[lf][f][i] = e[f] * inv;
    }

  if (kind == 0) {
#pragma unroll
    for (int lf = 0; lf < 5; ++lf)
#pragma unroll
      for (int i = 0; i < 4; ++i) {
        int l = l0 + lf * 16 + g * 4 + i;
        bool ok = (l < 300);
#pragma unroll
        for (int f = 0; f < 6; ++f) {
          float wv = ok ? c[lf][f][i] : 0.f;
          wrowB[((size_t)bn * 320 + l) * 96 + f * 16 + r] = (short)f2bf(wv);
        }
      }
  } else {
#pragma unroll
    for (int lf = 0; lf < 5; ++lf)
#pragma unroll
      for (int f = 0; f < 6; ++f) {
        int l = l0 + lf * 16 + g * 4;
        f32x4 wv = c[lf][f];
#pragma unroll
        for (int i = 0; i < 4; ++i) if (l + i >= 300) wv[i] = 0.f;
        *(f32x4*)(wcolT + ((size_t)bn * 96 + f * 16 + r) * 320 + l) = wv;
      }
  }
}

// ---------------- fused bilinear attention (MFMA, 8 waves) ----------------
__global__ __launch_bounds__(512) void attn_kernel(
    const short* __restrict__ wrowB, const float* __restrict__ wcolT,
    const short* __restrict__ vvT, float* __restrict__ ao) {
  __shared__ f32x4 cmb[3][2][4][64];
  int lh = blockIdx.x, n = blockIdx.y, b = blockIdx.z;
  int bn = b * 8 + n;
  int t = threadIdx.x, wave = t >> 6, lane = t & 63;
  int df = wave & 1, hh = wave >> 1;
  int lbase = lh * 64;
  int r = lane & 15, g = lane >> 4;

  short8v a[4][3];
  const short* wr = wrowB + (size_t)bn * 320 * 96;
#pragma unroll
  for (int lf = 0; lf < 4; ++lf)
#pragma unroll
    for (int ks = 0; ks < 3; ++ks)
      a[lf][ks] = *(const short8v*)(wr + (lbase + lf * 16 + r) * 96 + ks * 32 + g * 8);

  const short* vb = vvT + (size_t)bn * 294912 + (size_t)(df * 16 + r) * 9216 + hh * 24 * 96;
  const float* wcb = wcolT + ((size_t)bn * 96 + hh * 24) * 320 + lbase + g * 4;

  f32x4 acc[4] = {};
  short8v b0[3], b1[3];
  f32x4 w0[4], w1[4];
#pragma unroll
  for (int ks = 0; ks < 3; ++ks) b0[ks] = *(const short8v*)(vb + ks * 32 + g * 8);
#pragma unroll
  for (int lf = 0; lf < 4; ++lf) w0[lf] = *(const f32x4*)(wcb + lf * 16);

  for (int h2 = 0; h2 < 12; ++h2) {
    int h = h2 * 2;
#pragma unroll
    for (int ks = 0; ks < 3; ++ks) b1[ks] = *(const short8v*)(vb + (h + 1) * 96 + ks * 32 + g * 8);
#pragma unroll
    for (int lf = 0; lf < 4; ++lf) w1[lf] = *(const f32x4*)(wcb + (h + 1) * 320 + lf * 16);
    {
      f32x4 R[4] = {};
#pragma unroll
      for (int ks = 0; ks < 3; ++ks)
#pragma unroll
        for (int lf = 0; lf < 4; ++lf)
          R[lf] = __builtin_amdgcn_mfma_f32_16x16x32_bf16(a[lf][ks], b0[ks], R[lf], 0, 0, 0);
#pragma unroll
      for (int lf = 0; lf < 4; ++lf) acc[lf] += w0[lf] * R[lf];
    }
    if (h2 < 11) {
#pragma unroll
      for (int ks = 0; ks < 3; ++ks) b0[ks] = *(const short8v*)(vb + (h + 2) * 96 + ks * 32 + g * 8);
#pragma unroll
      for (int lf = 0; lf < 4; ++lf) w0[lf] = *(const f32x4*)(wcb + (h + 2) * 320 + lf * 16);
    }
    {
      f32x4 R[4] = {};
#pragma unroll
      for (int ks = 0; ks < 3; ++ks)
#pragma unroll
        for (int lf = 0; lf < 4; ++lf)
          R[lf] = __builtin_amdgcn_mfma_f32_16x16x32_bf16(a[lf][ks], b1[ks], R[lf], 0, 0, 0);
#pragma unroll
      for (int lf = 0; lf < 4; ++lf) acc[lf] += w1[lf] * R[lf];
    }
  }

  if (hh > 0) {
#pragma unroll
    for (int lf = 0; lf < 4; ++lf) cmb[hh - 1][df][lf][lane] = acc[lf];
  }
  __syncthreads();
  if (hh == 0) {
#pragma unroll
    for (int lf = 0; lf < 4; ++lf) {
      f32x4 o = acc[lf];
#pragma unroll
      for (int q = 0; q < 3; ++q) o += cmb[q][df][lf][lane];
#pragma unroll
      for (int i = 0; i < 4; ++i) {
        int l = lbase + lf * 16 + g * 4 + i;
        if (l < 300)
          ao[((size_t)b * 300 + l) * 256 + n * 32 + df * 16 + r] = o[i];
      }
    }
  }
}

// ---------------- launch ----------------
extern "C" void kernel_launch(void* const* d_in, const int* in_sizes, int n_in,
                              void* d_out, int out_size, void* d_ws, size_t ws_size,
                              hipStream_t stream) {
  const float* query_row = (const float*)d_in[0];
  const float* query_col = (const float*)d_in[1];
  const float* key_row   = (const float*)d_in[2];
  const float* key_col   = (const float*)d_in[3];
  const float* value     = (const float*)d_in[4];
  const float* W         = (const float*)d_in[5];  // (1280,256)
  const float* Bv        = (const float*)d_in[6];  // (1280,)
  const float* Wout      = (const float*)d_in[7];  // (256,256)
  const float* Bout      = (const float*)d_in[8];  // (256,)

  float* ws = (float*)d_ws;
  float* krm   = ws;                        // 196608 f
  float* kcm   = krm + 196608;              // 196608 f
  float* ao    = kcm + 196608;              // 614400 f
  float* wcolT = ao + 614400;               // 1966080 f
  short* qrb   = (short*)(wcolT + 1966080); // 614400 s
  short* qcb   = qrb + 614400;              // 614400 s
  short* krb   = qcb + 614400;              // 196608 s
  short* kcb   = krb + 196608;              // 196608 s
  short* wrowB = kcb + 196608;              // 1966080 s
  short* vvT   = wrowB + 1966080;           // 18874368 s
  short* Wb    = vvT + 18874368;            // 393216 s

  cvt_w_kernel<<<1536, 256, 0, stream>>>(W, Wout, Wb);
  mean_over_h_v3<<<768, 256, 0, stream>>>(key_row, krm);
  mean_over_w_v3<<<768, 256, 0, stream>>>(key_col, kcm);
  gemm_proj<<<dim3(75, 2), 256, 0, stream>>>(query_row, query_col, Wb, Bv,
                                             nullptr, qrb, qcb, SCALE_Q, 3);
  gemm_proj<<<dim3(24, 2), 256, 0, stream>>>(krm, kcm, Wb + 131072, Bv + 512,
                                             nullptr, krb, kcb, 1.f, 3);
  vproj_kernel<<<2304, 256, 0, stream>>>(value, Wb + 262144, Bv + 1024, vvT);
  scores_softmax_v2<<<dim3(4, 64, 2), 64, 0, stream>>>(qrb, qcb, krb, kcb, wrowB, wcolT);
  attn_kernel<<<dim3(5, 8, 8), 512, 0, stream>>>(wrowB, wcolT, vvT, ao);
  gemm_proj<<<dim3(75, 1), 256, 0, stream>>>(ao, nullptr, Wb + 327680, Bout,
                                             (float*)d_out, nullptr, nullptr, 1.f, 1);
}

// Round 10
// 158.760 us; speedup vs baseline: 1.2417x; 1.1040x over previous
//
#include <hip/hip_runtime.h>
#include <cstdint>

// MultiheadRCDA: N=8, L=300, HH=WW=96, E=256, NH=8, HD=32
// Round 10: vproj v8 — B-frags PINNED in VGPRs (asm pass-through defeats
// rematerialization; r9's VGPR_Count=84 proved B was being re-loaded per
// tile -> issue-bound at ~5TB/s). 144 rows/block (9 tiles) amortizes the
// one-time 128KB B load; triple-buffered GLL staging, exact counted vmcnt.

typedef __attribute__((ext_vector_type(8))) short short8v;  // bf16x8 MFMA frag
typedef __attribute__((ext_vector_type(4))) short short4v;  // 8B packed bf16
typedef __attribute__((ext_vector_type(4))) float f32x4;

#define SCALE_Q 0.17677669529663687f  // 32^-0.5

#define GLL16(gp, lp)                                                   \
  __builtin_amdgcn_global_load_lds(                                     \
      (const __attribute__((address_space(1))) void*)(gp),              \
      (__attribute__((address_space(3))) void*)(lp), 16, 0, 0)

__device__ __forceinline__ unsigned short f2bf(float x) {
  unsigned int u = __builtin_bit_cast(unsigned int, x);
  u += 0x7FFFu + ((u >> 16) & 1u);
  return (unsigned short)(u >> 16);
}

__device__ __forceinline__ unsigned int cvtpk(float a, float b) {
  unsigned int r;
  asm("v_cvt_pk_bf16_f32 %0, %1, %2" : "=v"(r) : "v"(a), "v"(b));
  return r;
}

__device__ __forceinline__ short8v pack8cvt(const f32x4& lo, const f32x4& hi) {
  union { short8v s; unsigned int u[4]; } z;
  z.u[0] = cvtpk(lo[0], lo[1]);
  z.u[1] = cvtpk(lo[2], lo[3]);
  z.u[2] = cvtpk(hi[0], hi[1]);
  z.u[3] = cvtpk(hi[2], hi[3]);
  return z.s;
}

__device__ __forceinline__ short4v pack4cvt(float a, float b, float c, float d) {
  union { short4v s; unsigned int u[2]; } z;
  z.u[0] = cvtpk(a, b);
  z.u[1] = cvtpk(c, d);
  return z.s;
}

__device__ __forceinline__ short8v pack8(const float4& fa, const float4& fb) {
  short8v v;
  v[0] = (short)f2bf(fa.x); v[1] = (short)f2bf(fa.y);
  v[2] = (short)f2bf(fa.z); v[3] = (short)f2bf(fa.w);
  v[4] = (short)f2bf(fb.x); v[5] = (short)f2bf(fb.y);
  v[6] = (short)f2bf(fb.z); v[7] = (short)f2bf(fb.w);
  return v;
}

// ---------------- weight fp32->bf16 ----------------
__global__ __launch_bounds__(256) void cvt_w_kernel(const float* __restrict__ w_in,
                                                    const float* __restrict__ w_out,
                                                    short* __restrict__ Wb) {
  int idx = blockIdx.x * 256 + threadIdx.x;  // 393216 total
  float v = (idx < 327680) ? w_in[idx] : w_out[idx - 327680];
  Wb[idx] = (short)f2bf(v);
}

// ---------------- mean kernels v3 ----------------
__global__ __launch_bounds__(256) void mean_over_h_v3(const float* __restrict__ in,
                                                      float* __restrict__ out) {
  __shared__ float4 part[256];
  int bw = blockIdx.x;  // b*96 + w
  int b = bw / 96, w = bw - b * 96;
  int t = threadIdx.x, e4 = t & 63, hq = t >> 6;
  const float4* p = (const float4*)(in + ((size_t)b * 9216 + w) * 256) + e4 +
                    (size_t)hq * 24 * 6144;
  float4 s = {0.f, 0.f, 0.f, 0.f};
#pragma unroll
  for (int i = 0; i < 24; ++i) {
    float4 v = p[(size_t)i * 6144];
    s.x += v.x; s.y += v.y; s.z += v.z; s.w += v.w;
  }
  part[t] = s;
  __syncthreads();
  if (t < 64) {
    float4 a = part[t], c = part[t + 64], d = part[t + 128], e = part[t + 192];
    float4 o;
    o.x = (a.x + c.x + d.x + e.x) * (1.f / 96.f);
    o.y = (a.y + c.y + d.y + e.y) * (1.f / 96.f);
    o.z = (a.z + c.z + d.z + e.z) * (1.f / 96.f);
    o.w = (a.w + c.w + d.w + e.w) * (1.f / 96.f);
    ((float4*)out)[(size_t)bw * 64 + t] = o;
  }
}

__global__ __launch_bounds__(256) void mean_over_w_v3(const float* __restrict__ in,
                                                      float* __restrict__ out) {
  __shared__ float4 part[256];
  int bh = blockIdx.x;  // b*96 + h
  int t = threadIdx.x, e4 = t & 63, wq = t >> 6;
  const float4* p = (const float4*)(in + (size_t)bh * 24576) + e4 + (size_t)wq * 24 * 64;
  float4 s = {0.f, 0.f, 0.f, 0.f};
#pragma unroll
  for (int i = 0; i < 24; ++i) {
    float4 v = p[(size_t)i * 64];
    s.x += v.x; s.y += v.y; s.z += v.z; s.w += v.w;
  }
  part[t] = s;
  __syncthreads();
  if (t < 64) {
    float4 a = part[t], c = part[t + 64], d = part[t + 128], e = part[t + 192];
    float4 o;
    o.x = (a.x + c.x + d.x + e.x) * (1.f / 96.f);
    o.y = (a.y + c.y + d.y + e.y) * (1.f / 96.f);
    o.z = (a.z + c.z + d.z + e.z) * (1.f / 96.f);
    o.w = (a.w + c.w + d.w + e.w) * (1.f / 96.f);
    ((float4*)out)[(size_t)bh * 64 + t] = o;
  }
}

// ---------------- bf16 MFMA projection GEMM (q/k/out), BM=32 ----------------
__global__ __launch_bounds__(256) void gemm_proj(
    const float* __restrict__ A0, const float* __restrict__ A1,
    const short* __restrict__ Wb, const float* __restrict__ bias,
    float* __restrict__ Cf, short* __restrict__ Cb0, short* __restrict__ Cb1,
    float scale, int mode) {
  __shared__ short As[32 * 264];
  int y = blockIdx.y;
  const float* A = y ? A1 : A0;
  short* Cb = y ? Cb1 : Cb0;
  const short* Wp = Wb + y * 65536;
  const float* bp = bias + y * 256;
  int t = threadIdx.x;
  int m0 = blockIdx.x * 32;
  int wave = t >> 6, lane = t & 63, r = lane & 15, g = lane >> 4;

  {
    int row = t >> 3, c0 = (t & 7) * 32;
    const float* ap = A + ((size_t)m0 + row) * 256 + c0;
    float4 ld[8];
#pragma unroll
    for (int j = 0; j < 8; ++j) ld[j] = *(const float4*)(ap + j * 4);
    short* dst = &As[row * 264 + c0];
#pragma unroll
    for (int j = 0; j < 4; ++j)
      *(short8v*)(dst + j * 8) = pack8(ld[2 * j], ld[2 * j + 1]);
  }
  __syncthreads();

  f32x4 acc[2][4] = {};
  const short* wbase = Wp + (size_t)(wave * 64 + r) * 256;
#pragma unroll
  for (int ks = 0; ks < 8; ++ks) {
    short8v af0 = *(const short8v*)&As[r * 264 + ks * 32 + g * 8];
    short8v af1 = *(const short8v*)&As[(16 + r) * 264 + ks * 32 + g * 8];
    short8v bf[4];
#pragma unroll
    for (int nf = 0; nf < 4; ++nf)
      bf[nf] = *(const short8v*)(wbase + nf * 16 * 256 + ks * 32 + g * 8);
#pragma unroll
    for (int nf = 0; nf < 4; ++nf) {
      acc[0][nf] = __builtin_amdgcn_mfma_f32_16x16x32_bf16(af0, bf[nf], acc[0][nf], 0, 0, 0);
      acc[1][nf] = __builtin_amdgcn_mfma_f32_16x16x32_bf16(af1, bf[nf], acc[1][nf], 0, 0, 0);
    }
  }

#pragma unroll
  for (int mf = 0; mf < 2; ++mf)
#pragma unroll
    for (int nf = 0; nf < 4; ++nf) {
      int nn = wave * 64 + nf * 16 + r;
      float bval = bp[nn];
#pragma unroll
      for (int i = 0; i < 4; ++i) {
        int m = m0 + mf * 16 + g * 4 + i;
        float val = (acc[mf][nf][i] + bval) * scale;
        if (mode == 1) {
          int bb = m / 300, ll = m - bb * 300;
          Cf[((size_t)ll * 8 + bb) * 256 + nn] = val;
        } else {  // mode 3
          Cb[(size_t)m * 256 + nn] = (short)f2bf(val);
        }
      }
    }
}

// ---------------- value projection v8 ----------------
// vvT[bn][d(32)][hw(9216)] bf16. grid 512 blocks x 144 rows (9 tiles of 16).
// B pinned in 128 VGPRs (asm pass-through), triple-buffered GLL staging,
// exact counted vmcnt (loads never drained mid-loop), Ts transpose epilogue.
__global__ __launch_bounds__(256, 2) void vproj_kernel(
    const float* __restrict__ A, const short* __restrict__ Wb,
    const float* __restrict__ bias, short* __restrict__ vvT) {
  __shared__ float buf[3][16 * 260];   // 3 x 16.6 KB
  __shared__ short Ts[4][64 * 20];     // per-wave 64ch x (16hw pad20)
  int t = threadIdx.x;
  int wave = t >> 6, lane = t & 63, r = lane & 15, g = lane >> 4;
  int m0g = blockIdx.x * 144;
  int b_ = blockIdx.x >> 6;            // 64 blocks per batch (9216/144)
  int hw00 = (blockIdx.x & 63) * 144;

  // hoist B: wave's 64 output channels, full K (32 frags = 128 VGPR), then PIN
  short8v bf[8][4];
  {
    const short* wbase = Wb + (size_t)(wave * 64 + r) * 256;
#pragma unroll
    for (int ks = 0; ks < 8; ++ks)
#pragma unroll
      for (int nf = 0; nf < 4; ++nf)
        bf[ks][nf] = *(const short8v*)(wbase + nf * 16 * 256 + ks * 32 + g * 8);
  }
#pragma unroll
  for (int ks = 0; ks < 8; ++ks)
#pragma unroll
    for (int nf = 0; nf < 4; ++nf)
      asm volatile("" : "+v"(bf[ks][nf]));  // defeat rematerialization
  float bias_v[4];
#pragma unroll
  for (int nf = 0; nf < 4; ++nf) bias_v[nf] = bias[wave * 64 + nf * 16 + r];

  // prologue: stage tiles 0..2 (4 GLLs each per wave; rows wave*4..+3)
#pragma unroll
  for (int q = 0; q < 3; ++q) {
#pragma unroll
    for (int i = 0; i < 4; ++i) {
      int row = wave * 4 + i;
      const float* gp = A + ((size_t)m0g + q * 16 + row) * 256 + lane * 4;
      GLL16(gp, &buf[q][row * 260]);
    }
  }

  int chg = wave * 64 + lane;
  short* vbase = vvT + (size_t)(b_ * 8 + (chg >> 5)) * 294912 +
                 (size_t)(chg & 31) * 9216 + hw00;
  const short* tsr = &Ts[wave][lane * 20];

#pragma unroll
  for (int tt = 0; tt < 9; ++tt) {
    // exact counted wait: tile tt's GLLs retired (in-order vmcnt retirement);
    // younger ops = GLL(tt+1,tt+2 if exist) + stores of iters tt-2,tt-1.
    if (tt == 0)      asm volatile("s_waitcnt vmcnt(8)" ::: "memory");
    else if (tt == 1) asm volatile("s_waitcnt vmcnt(10)" ::: "memory");
    else if (tt <= 6) asm volatile("s_waitcnt vmcnt(12)" ::: "memory");
    else if (tt == 7) asm volatile("s_waitcnt vmcnt(8)" ::: "memory");
    else              asm volatile("s_waitcnt vmcnt(4)" ::: "memory");
    __builtin_amdgcn_s_barrier();  // all waves' rows of tile tt present

    // compute tile tt from buf[tt%3]
    f32x4 acc[4] = {};
    const float* bp_ = &buf[tt % 3][0];
#pragma unroll
    for (int ks = 0; ks < 8; ++ks) {
      const float* p = bp_ + r * 260 + ks * 32 + g * 8;
      f32x4 lo = *(const f32x4*)p;
      f32x4 hi = *(const f32x4*)(p + 4);
      short8v af = pack8cvt(lo, hi);
#pragma unroll
      for (int nf = 0; nf < 4; ++nf)
        acc[nf] = __builtin_amdgcn_mfma_f32_16x16x32_bf16(af, bf[ks][nf], acc[nf], 0, 0, 0);
    }

    // per-wave Ts transpose (DS in-order per wave), then 2x16B channel stores
#pragma unroll
    for (int nf = 0; nf < 4; ++nf) {
      float bv = bias_v[nf];
      *(short4v*)&Ts[wave][(nf * 16 + r) * 20 + g * 4] =
          pack4cvt(acc[nf][0] + bv, acc[nf][1] + bv, acc[nf][2] + bv, acc[nf][3] + bv);
    }
    asm volatile("" ::: "memory");
    {
      short* gdst = vbase + tt * 16;
      *(short8v*)gdst = *(const short8v*)tsr;
      *(short8v*)(gdst + 8) = *(const short8v*)(tsr + 8);
    }
    asm volatile("" ::: "memory");

    __builtin_amdgcn_s_barrier();  // all waves done reading buf[tt%3]
    if (tt + 3 < 9) {              // refill it with tile tt+3
#pragma unroll
      for (int i = 0; i < 4; ++i) {
        int row = wave * 4 + i;
        const float* gp = A + ((size_t)m0g + (tt + 3) * 16 + row) * 256 + lane * 4;
        GLL16(gp, &buf[tt % 3][row * 260]);
      }
    }
  }
}

// ---------------- scores + softmax: MFMA + in-register softmax ----------------
__global__ __launch_bounds__(64) void scores_softmax_v2(
    const short* __restrict__ qrb, const short* __restrict__ qcb,
    const short* __restrict__ krb, const short* __restrict__ kcb,
    short* __restrict__ wrowB, float* __restrict__ wcolT) {
  int lchunk = blockIdx.x, bn = blockIdx.y, kind = blockIdx.z;
  int b = bn >> 3, n = bn & 7;
  int lane = threadIdx.x;
  int r = lane & 15, g = lane >> 4;
  const short* qb = kind ? qcb : qrb;
  const short* kb = kind ? kcb : krb;
  int l0 = lchunk * 80;

  short8v a[5], bfr[6];
#pragma unroll
  for (int lf = 0; lf < 5; ++lf) {
    int l = l0 + lf * 16 + r;
    if (l > 299) l = 299;
    a[lf] = *(const short8v*)(qb + ((size_t)b * 300 + l) * 256 + n * 32 + g * 8);
  }
#pragma unroll
  for (int f = 0; f < 6; ++f)
    bfr[f] = *(const short8v*)(kb + ((size_t)b * 96 + f * 16 + r) * 256 + n * 32 + g * 8);

  f32x4 c[5][6];
#pragma unroll
  for (int lf = 0; lf < 5; ++lf)
#pragma unroll
    for (int f = 0; f < 6; ++f) {
      f32x4 z = {};
      c[lf][f] = __builtin_amdgcn_mfma_f32_16x16x32_bf16(a[lf], bfr[f], z, 0, 0, 0);
    }

#pragma unroll
  for (int lf = 0; lf < 5; ++lf)
#pragma unroll
    for (int i = 0; i < 4; ++i) {
      float m = c[lf][0][i];
#pragma unroll
      for (int f = 1; f < 6; ++f) m = fmaxf(m, c[lf][f][i]);
#pragma unroll
      for (int mask = 1; mask <= 8; mask <<= 1) m = fmaxf(m, __shfl_xor(m, mask, 64));
      float e[6], s = 0.f;
#pragma unroll
      for (int f = 0; f < 6; ++f) { e[f] = __expf(c[lf][f][i] - m); s += e[f]; }
#pragma unroll
      for (int mask = 1; mask <= 8; mask <<= 1) s += __shfl_xor(s, mask, 64);
      float inv = 1.f / s;
#pragma unroll
      for (int f = 0; f < 6; ++f) c[lf][f][i] = e[f] * inv;
    }

  if (kind == 0) {
#pragma unroll
    for (int lf = 0; lf < 5; ++lf)
#pragma unroll
      for (int i = 0; i < 4; ++i) {
        int l = l0 + lf * 16 + g * 4 + i;
        bool ok = (l < 300);
#pragma unroll
        for (int f = 0; f < 6; ++f) {
          float wv = ok ? c[lf][f][i] : 0.f;
          wrowB[((size_t)bn * 320 + l) * 96 + f * 16 + r] = (short)f2bf(wv);
        }
      }
  } else {
#pragma unroll
    for (int lf = 0; lf < 5; ++lf)
#pragma unroll
      for (int f = 0; f < 6; ++f) {
        int l = l0 + lf * 16 + g * 4;
        f32x4 wv = c[lf][f];
#pragma unroll
        for (int i = 0; i < 4; ++i) if (l + i >= 300) wv[i] = 0.f;
        *(f32x4*)(wcolT + ((size_t)bn * 96 + f * 16 + r) * 320 + l) = wv;
      }
  }
}

// ---------------- fused bilinear attention (MFMA, 8 waves) ----------------
__global__ __launch_bounds__(512) void attn_kernel(
    const short* __restrict__ wrowB, const float* __restrict__ wcolT,
    const short* __restrict__ vvT, float* __restrict__ ao) {
  __shared__ f32x4 cmb[3][2][4][64];
  int lh = blockIdx.x, n = blockIdx.y, b = blockIdx.z;
  int bn = b * 8 + n;
  int t = threadIdx.x, wave = t >> 6, lane = t & 63;
  int df = wave & 1, hh = wave >> 1;
  int lbase = lh * 64;
  int r = lane & 15, g = lane >> 4;

  short8v a[4][3];
  const short* wr = wrowB + (size_t)bn * 320 * 96;
#pragma unroll
  for (int lf = 0; lf < 4; ++lf)
#pragma unroll
    for (int ks = 0; ks < 3; ++ks)
      a[lf][ks] = *(const short8v*)(wr + (lbase + lf * 16 + r) * 96 + ks * 32 + g * 8);

  const short* vb = vvT + (size_t)bn * 294912 + (size_t)(df * 16 + r) * 9216 + hh * 24 * 96;
  const float* wcb = wcolT + ((size_t)bn * 96 + hh * 24) * 320 + lbase + g * 4;

  f32x4 acc[4] = {};
  short8v b0[3], b1[3];
  f32x4 w0[4], w1[4];
#pragma unroll
  for (int ks = 0; ks < 3; ++ks) b0[ks] = *(const short8v*)(vb + ks * 32 + g * 8);
#pragma unroll
  for (int lf = 0; lf < 4; ++lf) w0[lf] = *(const f32x4*)(wcb + lf * 16);

  for (int h2 = 0; h2 < 12; ++h2) {
    int h = h2 * 2;
#pragma unroll
    for (int ks = 0; ks < 3; ++ks) b1[ks] = *(const short8v*)(vb + (h + 1) * 96 + ks * 32 + g * 8);
#pragma unroll
    for (int lf = 0; lf < 4; ++lf) w1[lf] = *(const f32x4*)(wcb + (h + 1) * 320 + lf * 16);
    {
      f32x4 R[4] = {};
#pragma unroll
      for (int ks = 0; ks < 3; ++ks)
#pragma unroll
        for (int lf = 0; lf < 4; ++lf)
          R[lf] = __builtin_amdgcn_mfma_f32_16x16x32_bf16(a[lf][ks], b0[ks], R[lf], 0, 0, 0);
#pragma unroll
      for (int lf = 0; lf < 4; ++lf) acc[lf] += w0[lf] * R[lf];
    }
    if (h2 < 11) {
#pragma unroll
      for (int ks = 0; ks < 3; ++ks) b0[ks] = *(const short8v*)(vb + (h + 2) * 96 + ks * 32 + g * 8);
#pragma unroll
      for (int lf = 0; lf < 4; ++lf) w0[lf] = *(const f32x4*)(wcb + (h + 2) * 320 + lf * 16);
    }
    {
      f32x4 R[4] = {};
#pragma unroll
      for (int ks = 0; ks < 3; ++ks)
#pragma unroll
        for (int lf = 0; lf < 4; ++lf)
          R[lf] = __builtin_amdgcn_mfma_f32_16x16x32_bf16(a[lf][ks], b1[ks], R[lf], 0, 0, 0);
#pragma unroll
      for (int lf = 0; lf < 4; ++lf) acc[lf] += w1[lf] * R[lf];
    }
  }

  if (hh > 0) {
#pragma unroll
    for (int lf = 0; lf < 4; ++lf) cmb[hh - 1][df][lf][lane] = acc[lf];
  }
  __syncthreads();
  if (hh == 0) {
#pragma unroll
    for (int lf = 0; lf < 4; ++lf) {
      f32x4 o = acc[lf];
#pragma unroll
      for (int q = 0; q < 3; ++q) o += cmb[q][df][lf][lane];
#pragma unroll
      for (int i = 0; i < 4; ++i) {
        int l = lbase + lf * 16 + g * 4 + i;
        if (l < 300)
          ao[((size_t)b * 300 + l) * 256 + n * 32 + df * 16 + r] = o[i];
      }
    }
  }
}

// ---------------- launch ----------------
extern "C" void kernel_launch(void* const* d_in, const int* in_sizes, int n_in,
                              void* d_out, int out_size, void* d_ws, size_t ws_size,
                              hipStream_t stream) {
  const float* query_row = (const float*)d_in[0];
  const float* query_col = (const float*)d_in[1];
  const float* key_row   = (const float*)d_in[2];
  const float* key_col   = (const float*)d_in[3];
  const float* value     = (const float*)d_in[4];
  const float* W         = (const float*)d_in[5];  // (1280,256)
  const float* Bv        = (const float*)d_in[6];  // (1280,)
  const float* Wout      = (const float*)d_in[7];  // (256,256)
  const float* Bout      = (const float*)d_in[8];  // (256,)

  float* ws = (float*)d_ws;
  float* krm   = ws;                        // 196608 f
  float* kcm   = krm + 196608;              // 196608 f
  float* ao    = kcm + 196608;              // 614400 f
  float* wcolT = ao + 614400;               // 1966080 f
  short* qrb   = (short*)(wcolT + 1966080); // 614400 s
  short* qcb   = qrb + 614400;              // 614400 s
  short* krb   = qcb + 614400;              // 196608 s
  short* kcb   = krb + 196608;              // 196608 s
  short* wrowB = kcb + 196608;              // 1966080 s
  short* vvT   = wrowB + 1966080;           // 18874368 s
  short* Wb    = vvT + 18874368;            // 393216 s

  cvt_w_kernel<<<1536, 256, 0, stream>>>(W, Wout, Wb);
  mean_over_h_v3<<<768, 256, 0, stream>>>(key_row, krm);
  mean_over_w_v3<<<768, 256, 0, stream>>>(key_col, kcm);
  gemm_proj<<<dim3(75, 2), 256, 0, stream>>>(query_row, query_col, Wb, Bv,
                                             nullptr, qrb, qcb, SCALE_Q, 3);
  gemm_proj<<<dim3(24, 2), 256, 0, stream>>>(krm, kcm, Wb + 131072, Bv + 512,
                                             nullptr, krb, kcb, 1.f, 3);
  vproj_kernel<<<512, 256, 0, stream>>>(value, Wb + 262144, Bv + 1024, vvT);
  scores_softmax_v2<<<dim3(4, 64, 2), 64, 0, stream>>>(qrb, qcb, krb, kcb, wrowB, wcolT);
  attn_kernel<<<dim3(5, 8, 8), 512, 0, stream>>>(wrowB, wcolT, vvT, ao);
  gemm_proj<<<dim3(75, 1), 256, 0, stream>>>(ao, nullptr, Wb + 327680, Bout,
                                             (float*)d_out, nullptr, nullptr, 1.f, 1);
}